// Round 10
// baseline (7463.648 us; speedup 1.0000x reference)
//
// AdiabaticTDDFTNN — exact reduced model, FLOAT32 outputs (round 10).
//
// Semantics (audited against the JAX reference 5+ times):
//  * psi0[:,0,:] = sqrt(0.5); rows 1..127 are exactly 0 and the Hamiltonian
//    ('ij,amj->ami' + elementwise field) never mixes rows -> evolve only
//    u = psi[:,0,:], one 128-site complex vector per batch element.
//  * z[l] = 1 - 2*Re(conj(psi[0,l])*psi[l,0]) -> z[l!=0] == 1 exactly,
//    z[0] = 1 - 2|u[0]|^2.
//  * mag[l] = 1 - 2|u[l]|^2.  z_ml rows: [mags reversed; z0=0 in row 127].
//  * 6.4/0.05 == 128.0 exactly in IEEE double -> T_INT=128, DT = 6.4/127.
//  * RK4 quirk: psi += (1/6)*(dt*k1 + 2*k2 + 2*k3 + k4)*dt.
//  * OUTPUT DTYPE IS FLOAT32 (reference outputs f32 + complex64):
//    d_out = [ z_ml : 2,097,152 f32 | psi : 4,194,304 f32 interleaved re,im ].

#include <hip/hip_runtime.h>

namespace v10 {
constexpr int BATCH = 128;
constexpr int SITES = 128;
constexpr int STEPS = 127;
constexpr int CHANS = 40;

struct Scratch {
  float  a[CHANS][SITES];   // conv activations
  float2 u[SITES];          // RK4 stage vector / psi row 0
  float  fA[SITES];         // v + h[t]
  float  fB[SITES];         // v + h[t+1]
  float  z0;                // z at site 0 (z elsewhere == 1 exactly)
};

__device__ __forceinline__ int wrap(int i) { return i & (SITES - 1); }
} // namespace v10

__global__ __launch_bounds__(512)
void adia_f32_v10(const float* __restrict__ hf,
                  const float* __restrict__ W0, const float* __restrict__ B0,
                  const float* __restrict__ W1, const float* __restrict__ B1,
                  const float* __restrict__ W2, const float* __restrict__ B2,
                  const float* __restrict__ W3, const float* __restrict__ B3,
                  float* __restrict__ zml,     // (B,128,L) f32
                  float* __restrict__ psf,     // (B,L,L) c64 as interleaved f32
                  int psiInterleaved, float dt)
{
  using namespace v10;
  __shared__ Scratch sm;

  const int  th   = threadIdx.x;
  const int  bi   = blockIdx.x;
  const int  site = th & (SITES - 1);
  const int  band = th >> 7;               // 0..3 -> 10 output channels each
  const bool own  = th < SITES;
  const float dtH = 0.5f * dt;
  const float dtS = dt * (1.0f / 6.0f);

  float uR = 0.70710678118654752440f, uI = 0.0f;    // sqrt(1/2)
  float kAccR = 0.0f, kAccI = 0.0f;

  // ---- constant output regions (rewritten every launch) ----
  if (own)                                           // z0 row (row 127) = 0
    zml[(size_t)bi * (STEPS + 1) * SITES + (size_t)STEPS * SITES + th] = 0.0f;
  if (psiInterleaved) {
    // psi rows 1..127 = 0: 127*128 c64 = 65,024 f32 = 16,256 float4 per batch
    float4* zp = reinterpret_cast<float4*>(psf + (size_t)bi * (2 * SITES * SITES) + 2 * SITES);
    const float4 nil = make_float4(0.f, 0.f, 0.f, 0.f);
    for (int j = th; j < 16256; j += 512) zp[j] = nil;
  } else {
    // real-only fallback layout (psi region = 2,097,152 f32)
    float4* zp = reinterpret_cast<float4*>(psf + (size_t)bi * (SITES * SITES) + SITES);
    const float4 nil = make_float4(0.f, 0.f, 0.f, 0.f);
    for (int j = th; j < 4064; j += 512) zp[j] = nil;
  }
  if (own) sm.u[th] = make_float2(uR, uI);

  for (int t = 0; t < STEPS; ++t) {
    if (th == 0) sm.z0 = 1.0f - 2.0f * (uR * uR + uI * uI);
    __syncthreads();

    // ---- conv 1 -> 40 (circular k=5; input z == 1 except site 0) ----
    {
      float xv[5];
      #pragma unroll
      for (int k = 0; k < 5; ++k)
        xv[k] = (wrap(site + k - 2) == 0) ? sm.z0 : 1.0f;
      #pragma unroll
      for (int j = 0; j < 10; ++j) {
        const int oc = band * 10 + j;
        float s = B0[oc];
        #pragma unroll
        for (int k = 0; k < 5; ++k) s = fmaf(W0[oc * 5 + k], xv[k], s);
        sm.a[oc][site] = fmaxf(s, 0.0f);
      }
    }
    __syncthreads();

    // ---- conv 40 -> 40, twice, ReLU ----
    for (int lay = 0; lay < 2; ++lay) {
      const float* __restrict__ Wp = lay ? W2 : W1;
      const float* __restrict__ Bp = lay ? B2 : B1;
      float acc[10];
      #pragma unroll
      for (int j = 0; j < 10; ++j) acc[j] = Bp[band * 10 + j];
      #pragma unroll 4
      for (int ic = 0; ic < CHANS; ++ic) {
        float xv[5];
        #pragma unroll
        for (int k = 0; k < 5; ++k) xv[k] = sm.a[ic][wrap(site + k - 2)];
        #pragma unroll
        for (int j = 0; j < 10; ++j) {
          const float* __restrict__ wrow = Wp + ((band * 10 + j) * CHANS + ic) * 5;
          #pragma unroll
          for (int k = 0; k < 5; ++k) acc[j] = fmaf(wrow[k], xv[k], acc[j]);
        }
      }
      __syncthreads();
      #pragma unroll
      for (int j = 0; j < 10; ++j) sm.a[band * 10 + j][site] = fmaxf(acc[j], 0.0f);
      __syncthreads();
    }

    // ---- conv 40 -> 1 (linear) + RK4 fields ----
    if (own) {
      float s = B3[0];
      #pragma unroll 4
      for (int ic = 0; ic < CHANS; ++ic) {
        const float* __restrict__ wrow = W3 + ic * 5;
        #pragma unroll
        for (int k = 0; k < 5; ++k)
          s = fmaf(wrow[k], sm.a[ic][wrap(th + k - 2)], s);
      }
      const size_t hx = (size_t)bi * ((STEPS + 1) * SITES) + (size_t)t * SITES + th;
      sm.fA[th] = s + hf[hx];
      sm.fB[th] = s + hf[hx + SITES];
    }
    __syncthreads();

    // ---- RK4, reference combine: u += dt/6*(dt*k1 + 2*k2 + 2*k3 + k4) ----
    #pragma unroll 1
    for (int st = 0; st < 4; ++st) {
      const bool fin = (st == 3);
      const float wgt = (st == 0) ? dt : (fin ? 1.0f : 2.0f);
      const float stp = (st == 2) ? dt : dtH;
      float nR = 0.0f, nI = 0.0f;
      if (own) {
        const float2 ym = sm.u[wrap(th - 1)];
        const float2 yc = sm.u[th];
        const float2 yp = sm.u[wrap(th + 1)];
        const float d  = 2.0f + (fin ? sm.fB[th] : sm.fA[th]);
        const float hR = fmaf(d, yc.x, -ym.x) - yp.x;   // Re(H y)
        const float hI = fmaf(d, yc.y, -ym.y) - yp.y;   // Im(H y)
        const float kR = hI, kI = -hR;                  // k = -i H y
        if (st == 0) { kAccR = wgt * kR;             kAccI = wgt * kI; }
        else         { kAccR = fmaf(wgt, kR, kAccR); kAccI = fmaf(wgt, kI, kAccI); }
        if (fin) { uR = fmaf(dtS, kAccR, uR); uI = fmaf(dtS, kAccI, uI); nR = uR; nI = uI; }
        else     { nR = fmaf(stp, kR, uR);    nI = fmaf(stp, kI, uI); }
      }
      __syncthreads();
      if (own) sm.u[th] = make_float2(nR, nI);
      __syncthreads();
    }

    // mag after step t -> z_ml row (126 - t), float32
    if (own)
      zml[(size_t)bi * ((STEPS + 1) * SITES) + (size_t)(STEPS - 1 - t) * SITES + th] =
          1.0f - 2.0f * (uR * uR + uI * uI);
  }

  // ---- final psi row 0, float32 ----
  if (own) {
    if (psiInterleaved) {
      const size_t o = (size_t)bi * (2 * SITES * SITES) + 2 * th;
      psf[o]     = uR;     // Re
      psf[o + 1] = uI;     // Im
    } else {
      psf[(size_t)bi * (SITES * SITES) + th] = uR;
    }
  }
}

extern "C" void kernel_launch(void* const* d_in, const int* in_sizes, int n_in,
                              void* d_out, int out_size, void* d_ws, size_t ws_size,
                              hipStream_t stream) {
  (void)d_ws; (void)ws_size;
  using namespace v10;

  // Inputs resolved by element count (robust to delivery-order differences).
  const float* in[9] = {nullptr};
  int seen200 = 0, seen40 = 0, seen8000 = 0;
  for (int i = 0; i < n_in && i < 16; ++i) {
    const int sz = in_sizes[i];
    const float* q = (const float*)d_in[i];
    if      (sz == 2097152) in[0] = q;                                     // h
    else if (sz == 8000)    { in[seen8000 ? 5 : 3] = q; ++seen8000; }      // Wc1,Wc2
    else if (sz == 200)     { in[seen200  ? 7 : 1] = q; ++seen200;  }      // Wc0,Wc3
    else if (sz == 40)      { in[seen40 == 0 ? 2 : (seen40 == 1 ? 4 : 6)] = q; ++seen40; }
    else if (sz == 1)       in[8] = q;                                     // bc3
  }
  bool resolved = true;
  for (int i = 0; i < 9; ++i) resolved = resolved && (in[i] != nullptr);
  if (!resolved) for (int i = 0; i < 9; ++i) in[i] = (const float*)d_in[i];

  const size_t zCount = (size_t)BATCH * (STEPS + 1) * SITES;  // 2,097,152 f32
  // psi region size (in f32) decides layout: complex64 interleaved needs
  // 2*B*L*L = 4,194,304 floats; anything smaller -> real-only fallback.
  const long long psiFloats = (long long)out_size - (long long)zCount;
  const int psiInterleaved = (psiFloats >= (long long)2 * SITES * SITES * BATCH) ? 1 : 0;

  float* zml = (float*)d_out;
  float* psf = zml + zCount;

  const float dt = (float)(6.4 / 127.0);   // int(6.4/0.05)==128 exactly

  hipLaunchKernelGGL(adia_f32_v10, dim3(BATCH), dim3(512), 0, stream,
                     in[0], in[1], in[2], in[3], in[4], in[5], in[6], in[7], in[8],
                     zml, psf, psiInterleaved, dt);
}

// Round 11
// 834.638 us; speedup vs baseline: 8.9424x; 8.9424x over previous
//
// AdiabaticTDDFTNN v11 — constant-column factorization + wave0-register RK4.
//
// Exact facts: psi rows 1..127 stay 0 -> dynamics = one 128-site complex
// vector u per batch. z[l!=0]==1 exactly -> conv input differs from the
// all-ones vector at ONE site, so non-constant activations live on
// 5/9/13/17 sites for L0/L1/L2/v; all other columns are step-invariant
// constants (precomputed once). DT = 6.4/127 (6.4/0.05 == 128.0 exactly).
// RK4 quirk: u += dt/6*(dt*k1 + 2*k2 + 2*k3 + k4). Outputs f32 (z_ml, c64 psi).

#include <hip/hip_runtime.h>

namespace v11 {
constexpr int B  = 128, L = 128, T = 127;
constexpr int NT = 576;        // 9 waves
constexpr int WS = 204;        // W1/W2 per-co row stride (floats): bank-spread, 16B-aligned
constexpr int AS = 44;         // act slot-row stride (floats): bank-spread, 16B-aligned
constexpr int SLOTS = 24;      // site offsets o in [-11..12] at slot o+11

struct SM {
  float w1[40 * WS];           // [co][k][ci(40)] padded   32640 B
  float w2[40 * WS];           //                          32640 B
  float a0[SLOTS * AS];        // [slot][ci] act0           4224 B
  float a1[SLOTS * AS];
  float a2[SLOTS * AS];
  float w0[200];               // [co][k]
  float w3t[5 * AS];           // [k][ci]
  float b1l[40], b2l[40];
  float pre0[40];              // b0 + sum_k w0   (pre-ReLU constant)
  float a0c[40], a1c[40], a2c[40];
  float v[20];                 // v at o=-8..8 (idx o+8)
  float z0, vc, b3s;
};
} // namespace v11

__global__ __launch_bounds__(576, 1)
void adia_v11(const float* __restrict__ hg0,
              const float* __restrict__ W0g, const float* __restrict__ B0g,
              const float* __restrict__ W1g, const float* __restrict__ B1g,
              const float* __restrict__ W2g, const float* __restrict__ B2g,
              const float* __restrict__ W3g, const float* __restrict__ B3g,
              float* __restrict__ zml, float* __restrict__ psf,
              int psiInterleaved, float dt)
{
  using namespace v11;
  __shared__ SM sm;
  const int tid  = threadIdx.x;
  const int bi   = blockIdx.x;
  const int lane = tid & 63;
  const float dtH = 0.5f * dt;
  const float dtS = dt * (1.0f / 6.0f);
  const float* __restrict__ hg = hg0 + (size_t)bi * (128 * L);

  // ---------------- one-time init ----------------
  for (int e = tid; e < 8000; e += NT) {
    const int co = e / 200, r = e - co * 200;
    const int ci = r / 5,   k = r - ci * 5;
    sm.w1[co * WS + k * 40 + ci] = W1g[e];
    sm.w2[co * WS + k * 40 + ci] = W2g[e];
  }
  for (int e = tid; e < 200; e += NT) {
    sm.w0[e] = W0g[e];
    const int ci = e / 5, k = e - ci * 5;
    sm.w3t[k * AS + ci] = W3g[e];
  }
  if (tid < 40) {
    sm.b1l[tid] = B1g[tid];
    sm.b2l[tid] = B2g[tid];
    float s = B0g[tid];
    #pragma unroll
    for (int k = 0; k < 5; ++k) s += W0g[tid * 5 + k];
    sm.pre0[tid] = s;
    sm.a0c[tid]  = fmaxf(s, 0.0f);
  }
  if (tid == 0) sm.b3s = B3g[0];
  __syncthreads();
  if (tid < 40) {                       // act1 constant column
    float acc = sm.b1l[tid];
    for (int ci = 0; ci < 40; ++ci) {
      const float x = sm.a0c[ci];
      #pragma unroll
      for (int k = 0; k < 5; ++k) acc = fmaf(sm.w1[tid * WS + k * 40 + ci], x, acc);
    }
    sm.a1c[tid] = fmaxf(acc, 0.0f);
  }
  __syncthreads();
  if (tid < 40) {                       // act2 constant column
    float acc = sm.b2l[tid];
    for (int ci = 0; ci < 40; ++ci) {
      const float x = sm.a1c[ci];
      #pragma unroll
      for (int k = 0; k < 5; ++k) acc = fmaf(sm.w2[tid * WS + k * 40 + ci], x, acc);
    }
    sm.a2c[tid] = fmaxf(acc, 0.0f);
  }
  __syncthreads();
  if (tid == 0) {                       // v constant
    float acc = sm.b3s;
    for (int ci = 0; ci < 40; ++ci) {
      #pragma unroll
      for (int k = 0; k < 5; ++k) acc = fmaf(sm.w3t[k * AS + ci], sm.a2c[ci], acc);
    }
    sm.vc = acc;
  }
  for (int e = tid; e < SLOTS * 40; e += NT) {   // pads = layer constants, forever
    const int slot = e / 40, ci = e - slot * 40;
    sm.a0[slot * AS + ci] = sm.a0c[ci];
    sm.a1[slot * AS + ci] = sm.a1c[ci];
    sm.a2[slot * AS + ci] = sm.a2c[ci];
  }

  // ---------------- constant output regions ----------------
  if (tid < 128) zml[(size_t)bi * (128 * L) + 127 * L + tid] = 0.0f;
  if (psiInterleaved) {
    float4* zp = reinterpret_cast<float4*>(psf + (size_t)bi * (2 * L * L) + 2 * L);
    const float4 nil = make_float4(0.f, 0.f, 0.f, 0.f);
    for (int j = tid; j < 16256; j += NT) zp[j] = nil;
  } else {
    float4* zp = reinterpret_cast<float4*>(psf + (size_t)bi * (L * L) + L);
    const float4 nil = make_float4(0.f, 0.f, 0.f, 0.f);
    for (int j = tid; j < 4064; j += NT) zp[j] = nil;
  }

  // ---------------- wave0 persistent state ----------------
  const float c0 = 0.70710678118654752440f;
  float uR0 = c0, uI0 = 0.f, uR1 = c0, uI1 = 0.f;
  float hA0 = 0.f, hA1 = 0.f, hB0 = 0.f, hB1 = 0.f, hP0 = 0.f, hP1 = 0.f;
  const int s0 = 2 * lane, s1 = s0 + 1;
  if (tid < 64) {
    const float2 h0 = *(const float2*)&hg[0 * L + s0];
    const float2 h1 = *(const float2*)&hg[1 * L + s0];
    hA0 = h0.x; hA1 = h0.y; hB0 = h1.x; hB1 = h1.y;
    if (lane == 0) sm.z0 = 1.0f - 2.0f * (uR0 * uR0 + uI0 * uI0);
  }
  __syncthreads();

  // ---------------- time loop ----------------
  for (int t = 0; t < T; ++t) {
    // prefetch h[t+2] early (hides under conv phases)
    if (tid < 64 && t + 2 < 128) {
      const float2 hp = *(const float2*)&hg[(t + 2) * L + s0];
      hP0 = hp.x; hP1 = hp.y;
    }

    // L0: only sites -2..2 differ from the constant column (1 FMA each)
    if (tid < 200) {
      const int co = tid / 5, j = tid - co * 5;     // o = j-2, k0 = 4-j
      const float val = fmaf(sm.w0[co * 5 + (4 - j)], sm.z0 - 1.0f, sm.pre0[co]);
      sm.a0[(j + 9) * AS + co] = fmaxf(val, 0.0f);
    }
    __syncthreads();

    // L1: 9 sites x 40 co, dot(200) via float4 quads
    if (tid < 360) {
      const int co = tid / 9, oo = tid - co * 9;
      float acc0 = sm.b1l[co], acc1 = 0.f;
      const float4* wrow = (const float4*)&sm.w1[co * WS];
      #pragma unroll
      for (int k = 0; k < 5; ++k) {
        const float4* arow = (const float4*)&sm.a0[(oo + k + 5) * AS];
        const float4* wk = wrow + k * 10;
        #pragma unroll
        for (int q = 0; q < 10; q += 2) {
          const float4 w = wk[q],     x = arow[q];
          acc0 = fmaf(w.x, x.x, fmaf(w.y, x.y, fmaf(w.z, x.z, fmaf(w.w, x.w, acc0))));
          const float4 w2 = wk[q + 1], x2 = arow[q + 1];
          acc1 = fmaf(w2.x, x2.x, fmaf(w2.y, x2.y, fmaf(w2.z, x2.z, fmaf(w2.w, x2.w, acc1))));
        }
      }
      sm.a1[(oo + 7) * AS + co] = fmaxf(acc0 + acc1, 0.0f);
    }
    __syncthreads();

    // L2: 13 sites x 40 co
    if (tid < 520) {
      const int co = tid / 13, oo = tid - co * 13;
      float acc0 = sm.b2l[co], acc1 = 0.f;
      const float4* wrow = (const float4*)&sm.w2[co * WS];
      #pragma unroll
      for (int k = 0; k < 5; ++k) {
        const float4* arow = (const float4*)&sm.a1[(oo + k + 3) * AS];
        const float4* wk = wrow + k * 10;
        #pragma unroll
        for (int q = 0; q < 10; q += 2) {
          const float4 w = wk[q],     x = arow[q];
          acc0 = fmaf(w.x, x.x, fmaf(w.y, x.y, fmaf(w.z, x.z, fmaf(w.w, x.w, acc0))));
          const float4 w2 = wk[q + 1], x2 = arow[q + 1];
          acc1 = fmaf(w2.x, x2.x, fmaf(w2.y, x2.y, fmaf(w2.z, x2.z, fmaf(w2.w, x2.w, acc1))));
        }
      }
      sm.a2[(oo + 5) * AS + co] = fmaxf(acc0 + acc1, 0.0f);
    }
    __syncthreads();

    // L3: 17 sites, single output channel (no ReLU)
    if (tid < 17) {
      float acc0 = sm.b3s, acc1 = 0.f;
      #pragma unroll
      for (int k = 0; k < 5; ++k) {
        const float4* arow = (const float4*)&sm.a2[(tid + k + 1) * AS];
        const float4* wk   = (const float4*)&sm.w3t[k * AS];
        #pragma unroll
        for (int q = 0; q < 10; q += 2) {
          const float4 w = wk[q],     x = arow[q];
          acc0 = fmaf(w.x, x.x, fmaf(w.y, x.y, fmaf(w.z, x.z, fmaf(w.w, x.w, acc0))));
          const float4 w2 = wk[q + 1], x2 = arow[q + 1];
          acc1 = fmaf(w2.x, x2.x, fmaf(w2.y, x2.y, fmaf(w2.z, x2.z, fmaf(w2.w, x2.w, acc1))));
        }
      }
      sm.v[tid] = acc0 + acc1;
    }
    __syncthreads();

    // fields + RK4 + mag + z0: entirely in wave0 registers (no barriers inside)
    if (tid < 64) {
      float v0 = sm.vc, v1 = sm.vc;
      if (s0 <= 8) v0 = sm.v[s0 + 8]; else if (s0 >= 120) v0 = sm.v[s0 - 120];
      if (s1 <= 8) v1 = sm.v[s1 + 8]; else if (s1 >= 120) v1 = sm.v[s1 - 120];
      const float f10 = v0 + hA0, f11 = v1 + hA1;
      const float f40 = v0 + hB0, f41 = v1 + hB1;

      float y0R = uR0, y0I = uI0, y1R = uR1, y1I = uI1;
      float aR0 = 0.f, aI0 = 0.f, aR1 = 0.f, aI1 = 0.f;
      #pragma unroll
      for (int st = 0; st < 4; ++st) {
        const bool fin = (st == 3);
        const float f0 = fin ? f40 : f10;
        const float f1 = fin ? f41 : f11;
        const float ymR = __shfl(y1R, (lane + 63) & 63);
        const float ymI = __shfl(y1I, (lane + 63) & 63);
        const float ypR = __shfl(y0R, (lane + 1) & 63);
        const float ypI = __shfl(y0I, (lane + 1) & 63);
        const float d0 = 2.0f + f0, d1 = 2.0f + f1;
        const float hRa = fmaf(d0, y0R, -ymR) - y1R;
        const float hIa = fmaf(d0, y0I, -ymI) - y1I;
        const float hRb = fmaf(d1, y1R, -y0R) - ypR;
        const float hIb = fmaf(d1, y1I, -y0I) - ypI;
        const float kR0 = hIa, kI0 = -hRa, kR1 = hIb, kI1 = -hRb;
        if (st == 0) { aR0 = dt * kR0; aI0 = dt * kI0; aR1 = dt * kR1; aI1 = dt * kI1; }
        else {
          const float w = fin ? 1.0f : 2.0f;
          aR0 = fmaf(w, kR0, aR0); aI0 = fmaf(w, kI0, aI0);
          aR1 = fmaf(w, kR1, aR1); aI1 = fmaf(w, kI1, aI1);
        }
        if (fin) {
          uR0 = fmaf(dtS, aR0, uR0); uI0 = fmaf(dtS, aI0, uI0);
          uR1 = fmaf(dtS, aR1, uR1); uI1 = fmaf(dtS, aI1, uI1);
        } else {
          const float stp = (st == 2) ? dt : dtH;
          y0R = fmaf(stp, kR0, uR0); y0I = fmaf(stp, kI0, uI0);
          y1R = fmaf(stp, kR1, uR1); y1I = fmaf(stp, kI1, uI1);
        }
      }

      const float m0 = 1.0f - 2.0f * (uR0 * uR0 + uI0 * uI0);
      const float m1 = 1.0f - 2.0f * (uR1 * uR1 + uI1 * uI1);
      *(float2*)&zml[(size_t)bi * (128 * L) + (size_t)(126 - t) * L + s0] =
          make_float2(m0, m1);
      if (lane == 0) sm.z0 = m0;
      hA0 = hB0; hA1 = hB1; hB0 = hP0; hB1 = hP1;
    }
    __syncthreads();
  }

  // ---------------- final psi row 0 ----------------
  if (tid < 64) {
    if (psiInterleaved) {
      *(float4*)&psf[(size_t)bi * (2 * L * L) + 4 * lane] =
          make_float4(uR0, uI0, uR1, uI1);
    } else {
      *(float2*)&psf[(size_t)bi * (L * L) + s0] = make_float2(uR0, uR1);
    }
  }
}

extern "C" void kernel_launch(void* const* d_in, const int* in_sizes, int n_in,
                              void* d_out, int out_size, void* d_ws, size_t ws_size,
                              hipStream_t stream) {
  (void)d_ws; (void)ws_size;
  using namespace v11;

  const float* in[9] = {nullptr};
  int seen200 = 0, seen40 = 0, seen8000 = 0;
  for (int i = 0; i < n_in && i < 16; ++i) {
    const int sz = in_sizes[i];
    const float* q = (const float*)d_in[i];
    if      (sz == 2097152) in[0] = q;
    else if (sz == 8000)    { in[seen8000 ? 5 : 3] = q; ++seen8000; }
    else if (sz == 200)     { in[seen200  ? 7 : 1] = q; ++seen200;  }
    else if (sz == 40)      { in[seen40 == 0 ? 2 : (seen40 == 1 ? 4 : 6)] = q; ++seen40; }
    else if (sz == 1)       in[8] = q;
  }
  bool ok = true;
  for (int i = 0; i < 9; ++i) ok = ok && (in[i] != nullptr);
  if (!ok) for (int i = 0; i < 9; ++i) in[i] = (const float*)d_in[i];

  const size_t zCount = (size_t)B * 128 * L;              // 2,097,152 f32
  const long long psiFloats = (long long)out_size - (long long)zCount;
  const int psiInterleaved =
      (psiFloats >= (long long)2 * L * L * B) ? 1 : 0;

  float* zml = (float*)d_out;
  float* psf = zml + zCount;
  const float dt = (float)(6.4 / 127.0);

  hipLaunchKernelGGL(adia_v11, dim3(B), dim3(NT), 0, stream,
                     in[0], in[1], in[2], in[3], in[4], in[5], in[6], in[7], in[8],
                     zml, psf, psiInterleaved, dt);
}

// Round 12
// 529.525 us; speedup vs baseline: 14.0950x; 1.5762x over previous
//
// AdiabaticTDDFTNN v12 — register-stationary weights + shfl reduction.
// Exact reduced model (unchanged semantics from v11, which passed):
//   dynamics = one 128-site complex vector u per batch; z[l!=0]==1 exactly;
//   conv nonconstant support 5/9/13/17 sites; DT = 6.4/127; RK4 quirk
//   u += dt/6*(dt*k1+2k2+2k3+k4); f32 outputs (z_ml, then c64 psi).

#include <hip/hip_runtime.h>

namespace v12 {
constexpr int B = 128, L = 128, T = 127;
constexpr int NT = 512;
constexpr int RS = 48;                 // activation row stride (floats), 16B-aligned
struct SM {
  float A0[13 * RS];                   // sites -6..6   (row = o+6)
  float A1[17 * RS];                   // sites -8..8   (row = o+8)
  float A2[21 * RS];                   // sites -10..10 (row = o+10)
  float W3T[5 * RS];                   // [k][ci48]
  float V[20];                         // v at o=-8..8 (idx o+8)
  float PRE0[40];
  float Z0, VC;
};
constexpr int SMF = sizeof(SM) / 4;
}

__global__ __launch_bounds__(512, 1)
void adia_v12(const float* __restrict__ hg0,
              const float* __restrict__ W0g, const float* __restrict__ B0g,
              const float* __restrict__ W1g, const float* __restrict__ B1g,
              const float* __restrict__ W2g, const float* __restrict__ B2g,
              const float* __restrict__ W3g, const float* __restrict__ B3g,
              float* __restrict__ zml, float* __restrict__ psf,
              int psiInterleaved, float dt)
{
  using namespace v12;
  __shared__ SM sm;
  const int tid  = threadIdx.x;
  const int bi   = blockIdx.x;
  const int lane = tid & 63;
  const float dtH = 0.5f * dt;
  const float dtS = dt * (1.0f / 6.0f);
  const float* __restrict__ hg = hg0 + (size_t)bi * (128 * L);

  // conv thread mapping: tid = co*12 + sh*4 + cg   (tid < 480)
  const bool convT = (tid < 480);
  const int  co = tid / 12;
  const int  rr = tid - co * 12;
  const int  sh = rr >> 2;             // 0..2 site-slice
  const int  cg = rr & 3;              // 0..3 ci-group (12 ci each, 40..47 pad)

  // L0 mapping: tid = co0*5 + j0 (tid < 200); site o=j0-2, weight k=4-j0
  const int  co0 = tid / 5;
  const int  j0  = tid - co0 * 5;

  // L3 mapping: i3 = tid-444 (68 threads): s3 = i3>>2 (o = s3-8), cg3 = i3&3
  const bool l3T = (tid >= 444);
  const int  i3  = tid - 444;
  const int  s3  = i3 >> 2;
  const int  cg3 = i3 & 3;

  // ---- one-time: weights into registers ----
  float4 w1r[15], w2r[15];
  float  b1r = 0.f, b2r = 0.f;
  if (convT) {
    b1r = B1g[co]; b2r = B2g[co];
    #pragma unroll
    for (int k = 0; k < 5; ++k) {
      #pragma unroll
      for (int q = 0; q < 3; ++q) {
        float4 a, b;
        #pragma unroll
        for (int e = 0; e < 4; ++e) {
          const int ci = cg * 12 + q * 4 + e;
          float va = 0.f, vb = 0.f;
          if (ci < 40) {
            va = W1g[(co * 40 + ci) * 5 + k];
            vb = W2g[(co * 40 + ci) * 5 + k];
          }
          (&a.x)[e] = va; (&b.x)[e] = vb;
        }
        w1r[k * 3 + q] = a; w2r[k * 3 + q] = b;
      }
    }
  }
  const float b3r = l3T ? B3g[0] : 0.f;
  const float w0r = (tid < 200) ? W0g[co0 * 5 + (4 - j0)] : 0.f;

  // ---- zero LDS + constant output regions ----
  for (int e = tid; e < SMF; e += NT) ((float*)&sm)[e] = 0.f;
  if (tid < 128) zml[(size_t)bi * (128 * L) + 127 * L + tid] = 0.0f;
  if (psiInterleaved) {
    float4* zp = reinterpret_cast<float4*>(psf + (size_t)bi * (2 * L * L) + 2 * L);
    const float4 nil = make_float4(0.f, 0.f, 0.f, 0.f);
    for (int j = tid; j < 16256; j += NT) zp[j] = nil;
  } else {
    float4* zp = reinterpret_cast<float4*>(psf + (size_t)bi * (L * L) + L);
    const float4 nil = make_float4(0.f, 0.f, 0.f, 0.f);
    for (int j = tid; j < 4064; j += NT) zp[j] = nil;
  }
  __syncthreads();

  // ---- constants: pre0/a0c ; W3T ----
  if (tid < 40) {
    float s = B0g[tid];
    #pragma unroll
    for (int k = 0; k < 5; ++k) s += W0g[tid * 5 + k];
    sm.PRE0[tid] = s;
    const float a0c = fmaxf(s, 0.0f);
    #pragma unroll
    for (int r = 0; r < 4; ++r) {            // halo rows 0-3 and 9-12
      sm.A0[r * RS + tid]       = a0c;
      sm.A0[(9 + r) * RS + tid] = a0c;
    }
  }
  for (int e = tid; e < 240; e += NT) {
    const int k = e / RS, c = e - k * RS;
    sm.W3T[e] = (c < 40) ? W3g[c * 5 + k] : 0.f;
  }
  __syncthreads();
  const float pre0r = (tid < 200) ? sm.PRE0[co0] : 0.f;

  // ---- a1c: conv of constant column (input row = A0 halo row 0) ----
  if (convT) {
    float4 ac0 = make_float4(0,0,0,0), ac1 = ac0, ac2 = ac0;
    const float4* ar = (const float4*)&sm.A0[cg * 12];
    const float4 a0v = ar[0], a1v = ar[1], a2v = ar[2];
    #pragma unroll
    for (int k = 0; k < 5; ++k) {
      const float4 wa = w1r[k*3], wb = w1r[k*3+1], wc = w1r[k*3+2];
      ac0.x = fmaf(wa.x, a0v.x, ac0.x); ac0.y = fmaf(wa.y, a0v.y, ac0.y);
      ac0.z = fmaf(wa.z, a0v.z, ac0.z); ac0.w = fmaf(wa.w, a0v.w, ac0.w);
      ac1.x = fmaf(wb.x, a1v.x, ac1.x); ac1.y = fmaf(wb.y, a1v.y, ac1.y);
      ac1.z = fmaf(wb.z, a1v.z, ac1.z); ac1.w = fmaf(wb.w, a1v.w, ac1.w);
      ac2.x = fmaf(wc.x, a2v.x, ac2.x); ac2.y = fmaf(wc.y, a2v.y, ac2.y);
      ac2.z = fmaf(wc.z, a2v.z, ac2.z); ac2.w = fmaf(wc.w, a2v.w, ac2.w);
    }
    float red = (ac0.x+ac0.y+ac0.z+ac0.w)+(ac1.x+ac1.y+ac1.z+ac1.w)+(ac2.x+ac2.y+ac2.z+ac2.w);
    red += __shfl_xor(red, 1); red += __shfl_xor(red, 2);
    if (cg == 0 && sh == 0) {
      const float a1c = fmaxf(red + b1r, 0.0f);
      #pragma unroll
      for (int r = 0; r < 4; ++r) {          // halo rows 0-3 and 13-16
        sm.A1[r * RS + co]        = a1c;
        sm.A1[(13 + r) * RS + co] = a1c;
      }
    }
  }
  __syncthreads();

  // ---- a2c ----
  if (convT) {
    float4 ac0 = make_float4(0,0,0,0), ac1 = ac0, ac2 = ac0;
    const float4* ar = (const float4*)&sm.A1[cg * 12];
    const float4 a0v = ar[0], a1v = ar[1], a2v = ar[2];
    #pragma unroll
    for (int k = 0; k < 5; ++k) {
      const float4 wa = w2r[k*3], wb = w2r[k*3+1], wc = w2r[k*3+2];
      ac0.x = fmaf(wa.x, a0v.x, ac0.x); ac0.y = fmaf(wa.y, a0v.y, ac0.y);
      ac0.z = fmaf(wa.z, a0v.z, ac0.z); ac0.w = fmaf(wa.w, a0v.w, ac0.w);
      ac1.x = fmaf(wb.x, a1v.x, ac1.x); ac1.y = fmaf(wb.y, a1v.y, ac1.y);
      ac1.z = fmaf(wb.z, a1v.z, ac1.z); ac1.w = fmaf(wb.w, a1v.w, ac1.w);
      ac2.x = fmaf(wc.x, a2v.x, ac2.x); ac2.y = fmaf(wc.y, a2v.y, ac2.y);
      ac2.z = fmaf(wc.z, a2v.z, ac2.z); ac2.w = fmaf(wc.w, a2v.w, ac2.w);
    }
    float red = (ac0.x+ac0.y+ac0.z+ac0.w)+(ac1.x+ac1.y+ac1.z+ac1.w)+(ac2.x+ac2.y+ac2.z+ac2.w);
    red += __shfl_xor(red, 1); red += __shfl_xor(red, 2);
    if (cg == 0 && sh == 0) {
      const float a2c = fmaxf(red + b2r, 0.0f);
      #pragma unroll
      for (int r = 0; r < 4; ++r) {          // halo rows 0-3 and 17-20
        sm.A2[r * RS + co]        = a2c;
        sm.A2[(17 + r) * RS + co] = a2c;
      }
    }
  }
  __syncthreads();

  // ---- vc ----
  if (l3T && s3 == 0) {
    float acc = 0.f;
    #pragma unroll
    for (int k = 0; k < 5; ++k) {
      const float4* wr = (const float4*)&sm.W3T[k * RS + cg3 * 12];
      const float4* ar = (const float4*)&sm.A2[cg3 * 12];
      #pragma unroll
      for (int q = 0; q < 3; ++q) {
        const float4 w = wr[q], a = ar[q];
        acc = fmaf(w.x, a.x, fmaf(w.y, a.y, fmaf(w.z, a.z, fmaf(w.w, a.w, acc))));
      }
    }
    acc += __shfl_xor(acc, 1); acc += __shfl_xor(acc, 2);
    if (cg3 == 0) sm.VC = acc + b3r;
  }
  __syncthreads();

  // ---- wave0 persistent state ----
  const float c0 = 0.70710678118654752440f;
  float uR0 = c0, uI0 = 0.f, uR1 = c0, uI1 = 0.f;
  float hA0 = 0.f, hA1 = 0.f, hB0 = 0.f, hB1 = 0.f, hP0 = 0.f, hP1 = 0.f;
  const int s0 = 2 * lane, s1 = s0 + 1;
  if (tid < 64) {
    const float2 h0 = *(const float2*)&hg[0 * L + s0];
    const float2 h1 = *(const float2*)&hg[1 * L + s0];
    hA0 = h0.x; hA1 = h0.y; hB0 = h1.x; hB1 = h1.y;
    if (lane == 0) sm.Z0 = 1.0f - 2.0f * (uR0 * uR0 + uI0 * uI0);
  }
  __syncthreads();

  // ================= time loop =================
  for (int t = 0; t < T; ++t) {
    if (tid < 64 && t + 2 < 128) {
      const float2 hp = *(const float2*)&hg[(t + 2) * L + s0];
      hP0 = hp.x; hP1 = hp.y;
    }
    // L0: sites -2..2 (row j0+4), 1 FMA each
    if (tid < 200)
      sm.A0[(j0 + 4) * RS + co0] = fmaxf(fmaf(w0r, sm.Z0 - 1.0f, pre0r), 0.0f);
    __syncthreads();

    // L1: 9 sites (3 per sh), rows o+k+4
    if (convT) {
      const int baseo = -4 + sh * 3;
      #pragma unroll
      for (int i = 0; i < 3; ++i) {
        const int o = baseo + i;
        float4 ac0 = make_float4(0,0,0,0), ac1 = ac0, ac2 = ac0;
        #pragma unroll
        for (int k = 0; k < 5; ++k) {
          const float4* ar = (const float4*)&sm.A0[(o + k + 4) * RS + cg * 12];
          const float4 a0v = ar[0], a1v = ar[1], a2v = ar[2];
          const float4 wa = w1r[k*3], wb = w1r[k*3+1], wc = w1r[k*3+2];
          ac0.x = fmaf(wa.x, a0v.x, ac0.x); ac0.y = fmaf(wa.y, a0v.y, ac0.y);
          ac0.z = fmaf(wa.z, a0v.z, ac0.z); ac0.w = fmaf(wa.w, a0v.w, ac0.w);
          ac1.x = fmaf(wb.x, a1v.x, ac1.x); ac1.y = fmaf(wb.y, a1v.y, ac1.y);
          ac1.z = fmaf(wb.z, a1v.z, ac1.z); ac1.w = fmaf(wb.w, a1v.w, ac1.w);
          ac2.x = fmaf(wc.x, a2v.x, ac2.x); ac2.y = fmaf(wc.y, a2v.y, ac2.y);
          ac2.z = fmaf(wc.z, a2v.z, ac2.z); ac2.w = fmaf(wc.w, a2v.w, ac2.w);
        }
        float red = (ac0.x+ac0.y+ac0.z+ac0.w)+(ac1.x+ac1.y+ac1.z+ac1.w)+(ac2.x+ac2.y+ac2.z+ac2.w);
        red += __shfl_xor(red, 1); red += __shfl_xor(red, 2);
        if (cg == 0) sm.A1[(o + 8) * RS + co] = fmaxf(red + b1r, 0.0f);
      }
    }
    __syncthreads();

    // L2: 13 sites (5 per sh with benign overlap), rows o+k+6
    if (convT) {
      const int baseo = (sh == 0) ? -6 : ((sh == 1) ? -2 : 2);
      #pragma unroll
      for (int i = 0; i < 5; ++i) {
        const int o = baseo + i;
        float4 ac0 = make_float4(0,0,0,0), ac1 = ac0, ac2 = ac0;
        #pragma unroll
        for (int k = 0; k < 5; ++k) {
          const float4* ar = (const float4*)&sm.A1[(o + k + 6) * RS + cg * 12];
          const float4 a0v = ar[0], a1v = ar[1], a2v = ar[2];
          const float4 wa = w2r[k*3], wb = w2r[k*3+1], wc = w2r[k*3+2];
          ac0.x = fmaf(wa.x, a0v.x, ac0.x); ac0.y = fmaf(wa.y, a0v.y, ac0.y);
          ac0.z = fmaf(wa.z, a0v.z, ac0.z); ac0.w = fmaf(wa.w, a0v.w, ac0.w);
          ac1.x = fmaf(wb.x, a1v.x, ac1.x); ac1.y = fmaf(wb.y, a1v.y, ac1.y);
          ac1.z = fmaf(wb.z, a1v.z, ac1.z); ac1.w = fmaf(wb.w, a1v.w, ac1.w);
          ac2.x = fmaf(wc.x, a2v.x, ac2.x); ac2.y = fmaf(wc.y, a2v.y, ac2.y);
          ac2.z = fmaf(wc.z, a2v.z, ac2.z); ac2.w = fmaf(wc.w, a2v.w, ac2.w);
        }
        float red = (ac0.x+ac0.y+ac0.z+ac0.w)+(ac1.x+ac1.y+ac1.z+ac1.w)+(ac2.x+ac2.y+ac2.z+ac2.w);
        red += __shfl_xor(red, 1); red += __shfl_xor(red, 2);
        if (cg == 0) sm.A2[(o + 10) * RS + co] = fmaxf(red + b2r, 0.0f);
      }
    }
    __syncthreads();

    // L3: 17 sites x 4 cg, rows o+k+8, weights from LDS (broadcast)
    if (l3T) {
      const int o = s3 - 8;
      float acc = 0.f;
      #pragma unroll
      for (int k = 0; k < 5; ++k) {
        const float4* wr = (const float4*)&sm.W3T[k * RS + cg3 * 12];
        const float4* ar = (const float4*)&sm.A2[(o + k + 8) * RS + cg3 * 12];
        #pragma unroll
        for (int q = 0; q < 3; ++q) {
          const float4 w = wr[q], a = ar[q];
          acc = fmaf(w.x, a.x, fmaf(w.y, a.y, fmaf(w.z, a.z, fmaf(w.w, a.w, acc))));
        }
      }
      acc += __shfl_xor(acc, 1); acc += __shfl_xor(acc, 2);
      if (cg3 == 0) sm.V[s3] = acc + b3r;
    }
    __syncthreads();

    // RK4 + mag + z0 (wave0 registers; v11-proven)
    if (tid < 64) {
      float v0 = sm.VC, v1 = sm.VC;
      if (s0 <= 8) v0 = sm.V[s0 + 8]; else if (s0 >= 120) v0 = sm.V[s0 - 120];
      if (s1 <= 8) v1 = sm.V[s1 + 8]; else if (s1 >= 120) v1 = sm.V[s1 - 120];
      const float f10 = v0 + hA0, f11 = v1 + hA1;
      const float f40 = v0 + hB0, f41 = v1 + hB1;

      float y0R = uR0, y0I = uI0, y1R = uR1, y1I = uI1;
      float aR0 = 0.f, aI0 = 0.f, aR1 = 0.f, aI1 = 0.f;
      #pragma unroll
      for (int st = 0; st < 4; ++st) {
        const bool fin = (st == 3);
        const float f0 = fin ? f40 : f10;
        const float f1 = fin ? f41 : f11;
        const float ymR = __shfl(y1R, (lane + 63) & 63);
        const float ymI = __shfl(y1I, (lane + 63) & 63);
        const float ypR = __shfl(y0R, (lane + 1) & 63);
        const float ypI = __shfl(y0I, (lane + 1) & 63);
        const float d0 = 2.0f + f0, d1 = 2.0f + f1;
        const float hRa = fmaf(d0, y0R, -ymR) - y1R;
        const float hIa = fmaf(d0, y0I, -ymI) - y1I;
        const float hRb = fmaf(d1, y1R, -y0R) - ypR;
        const float hIb = fmaf(d1, y1I, -y0I) - ypI;
        const float kR0 = hIa, kI0 = -hRa, kR1 = hIb, kI1 = -hRb;
        if (st == 0) { aR0 = dt * kR0; aI0 = dt * kI0; aR1 = dt * kR1; aI1 = dt * kI1; }
        else {
          const float w = fin ? 1.0f : 2.0f;
          aR0 = fmaf(w, kR0, aR0); aI0 = fmaf(w, kI0, aI0);
          aR1 = fmaf(w, kR1, aR1); aI1 = fmaf(w, kI1, aI1);
        }
        if (fin) {
          uR0 = fmaf(dtS, aR0, uR0); uI0 = fmaf(dtS, aI0, uI0);
          uR1 = fmaf(dtS, aR1, uR1); uI1 = fmaf(dtS, aI1, uI1);
        } else {
          const float stp = (st == 2) ? dt : dtH;
          y0R = fmaf(stp, kR0, uR0); y0I = fmaf(stp, kI0, uI0);
          y1R = fmaf(stp, kR1, uR1); y1I = fmaf(stp, kI1, uI1);
        }
      }
      const float m0 = 1.0f - 2.0f * (uR0 * uR0 + uI0 * uI0);
      const float m1 = 1.0f - 2.0f * (uR1 * uR1 + uI1 * uI1);
      *(float2*)&zml[(size_t)bi * (128 * L) + (size_t)(126 - t) * L + s0] =
          make_float2(m0, m1);
      if (lane == 0) sm.Z0 = m0;
      hA0 = hB0; hA1 = hB1; hB0 = hP0; hB1 = hP1;
    }
    __syncthreads();
  }

  // ---- final psi row 0 ----
  if (tid < 64) {
    if (psiInterleaved) {
      *(float4*)&psf[(size_t)bi * (2 * L * L) + 4 * lane] =
          make_float4(uR0, uI0, uR1, uI1);
    } else {
      *(float2*)&psf[(size_t)bi * (L * L) + s0] = make_float2(uR0, uR1);
    }
  }
}

extern "C" void kernel_launch(void* const* d_in, const int* in_sizes, int n_in,
                              void* d_out, int out_size, void* d_ws, size_t ws_size,
                              hipStream_t stream) {
  (void)d_ws; (void)ws_size;
  using namespace v12;

  const float* in[9] = {nullptr};
  int seen200 = 0, seen40 = 0, seen8000 = 0;
  for (int i = 0; i < n_in && i < 16; ++i) {
    const int sz = in_sizes[i];
    const float* q = (const float*)d_in[i];
    if      (sz == 2097152) in[0] = q;
    else if (sz == 8000)    { in[seen8000 ? 5 : 3] = q; ++seen8000; }
    else if (sz == 200)     { in[seen200  ? 7 : 1] = q; ++seen200;  }
    else if (sz == 40)      { in[seen40 == 0 ? 2 : (seen40 == 1 ? 4 : 6)] = q; ++seen40; }
    else if (sz == 1)       in[8] = q;
  }
  bool ok = true;
  for (int i = 0; i < 9; ++i) ok = ok && (in[i] != nullptr);
  if (!ok) for (int i = 0; i < 9; ++i) in[i] = (const float*)d_in[i];

  const size_t zCount = (size_t)B * 128 * L;
  const long long psiFloats = (long long)out_size - (long long)zCount;
  const int psiInterleaved = (psiFloats >= (long long)2 * L * L * B) ? 1 : 0;

  float* zml = (float*)d_out;
  float* psf = zml + zCount;
  const float dt = (float)(6.4 / 127.0);

  hipLaunchKernelGGL(adia_v12, dim3(B), dim3(NT), 0, stream,
                     in[0], in[1], in[2], in[3], in[4], in[5], in[6], in[7], in[8],
                     zml, psf, psiInterleaved, dt);
}

// Round 14
// 509.586 us; speedup vs baseline: 14.6465x; 1.0391x over previous
//
// AdiabaticTDDFTNN v14 — v13 with the L2 second-pass off-by-one FIXED.
// (v13 regression: CONV_SITE(R, i+1) read window rows +1 and OOB R[6];
//  correct is CONV_SITE(R, i) → site b+3 uses rows b+9..b+13, b+4 uses b+10..b+14.)
// Semantics identical to v12 (passed): reduced single-row model, z[l!=0]==1
// exact, conv support 5/9/13/17, DT=6.4/127, RK4 quirk, f32 outputs.

#include <hip/hip_runtime.h>

namespace v14 {
constexpr int B = 128, L = 128, T = 127;
constexpr int NT = 512;
constexpr int RS = 52;                 // row stride: delta ≡ 20 mod 32 → ≤2-way conflicts
struct SM {
  float A0[13 * RS];                   // sites -6..6   (row = o+6)
  float A1[17 * RS];                   // sites -8..8   (row = o+8)
  float A2[21 * RS];                   // sites -10..10 (row = o+10)
  float W3T[5 * RS];                   // [k][ci48]
  float V[20];                         // v at o=-8..8 (idx o+8)
  float PRE0[40];
  float Z0, VC;
};
constexpr int SMF = sizeof(SM) / 4;
}

// Accumulate one output site from window regs RARR (rows I..I+4) against WREG.
#define CONV_SITE(RARR, I, WREG, BIAS, DSTPTR)                                  \
  {                                                                             \
    float4 ac0 = make_float4(0,0,0,0), ac1 = ac0, ac2 = ac0;                    \
    _Pragma("unroll")                                                           \
    for (int k = 0; k < 5; ++k) {                                               \
      const float4 a0v = RARR[(I) + k][0], a1v = RARR[(I) + k][1],              \
                   a2v = RARR[(I) + k][2];                                      \
      const float4 wa = WREG[k*3], wb = WREG[k*3+1], wc = WREG[k*3+2];          \
      ac0.x = fmaf(wa.x, a0v.x, ac0.x); ac0.y = fmaf(wa.y, a0v.y, ac0.y);       \
      ac0.z = fmaf(wa.z, a0v.z, ac0.z); ac0.w = fmaf(wa.w, a0v.w, ac0.w);       \
      ac1.x = fmaf(wb.x, a1v.x, ac1.x); ac1.y = fmaf(wb.y, a1v.y, ac1.y);       \
      ac1.z = fmaf(wb.z, a1v.z, ac1.z); ac1.w = fmaf(wb.w, a1v.w, ac1.w);       \
      ac2.x = fmaf(wc.x, a2v.x, ac2.x); ac2.y = fmaf(wc.y, a2v.y, ac2.y);       \
      ac2.z = fmaf(wc.z, a2v.z, ac2.z); ac2.w = fmaf(wc.w, a2v.w, ac2.w);       \
    }                                                                           \
    float red = (ac0.x+ac0.y+ac0.z+ac0.w) + (ac1.x+ac1.y+ac1.z+ac1.w)          \
              + (ac2.x+ac2.y+ac2.z+ac2.w);                                      \
    red += __shfl_xor(red, 1); red += __shfl_xor(red, 2);                       \
    if (cg == 0) *(DSTPTR) = fmaxf(red + (BIAS), 0.0f);                         \
  }

__global__ __launch_bounds__(512, 2)
void adia_v14(const float* __restrict__ hg0,
              const float* __restrict__ W0g, const float* __restrict__ B0g,
              const float* __restrict__ W1g, const float* __restrict__ B1g,
              const float* __restrict__ W2g, const float* __restrict__ B2g,
              const float* __restrict__ W3g, const float* __restrict__ B3g,
              float* __restrict__ zml, float* __restrict__ psf,
              int psiInterleaved, float dt)
{
  using namespace v14;
  __shared__ SM sm;
  const int tid  = threadIdx.x;
  const int bi   = blockIdx.x;
  const int lane = tid & 63;
  const float dtH = 0.5f * dt;
  const float dtS = dt * (1.0f / 6.0f);
  const float* __restrict__ hg = hg0 + (size_t)bi * (128 * L);

  const bool convT = (tid < 480);
  const int  co = tid / 12;
  const int  rr = tid - co * 12;
  const int  sh = rr >> 2;
  const int  cg = rr & 3;

  const int  co0 = tid / 5;
  const int  j0  = tid - co0 * 5;

  const bool l3T = (tid >= 444);
  const int  i3  = tid - 444;
  const int  s3  = i3 >> 2;
  const int  cg3 = i3 & 3;

  // ---- one-time: W1/W2 slices into registers ----
  float4 w1r[15], w2r[15];
  float  b1r = 0.f, b2r = 0.f;
  if (convT) {
    b1r = B1g[co]; b2r = B2g[co];
    #pragma unroll
    for (int k = 0; k < 5; ++k)
      #pragma unroll
      for (int q = 0; q < 3; ++q) {
        float4 a, b;
        #pragma unroll
        for (int e = 0; e < 4; ++e) {
          const int ci = cg * 12 + q * 4 + e;
          float va = 0.f, vb = 0.f;
          if (ci < 40) {
            va = W1g[(co * 40 + ci) * 5 + k];
            vb = W2g[(co * 40 + ci) * 5 + k];
          }
          (&a.x)[e] = va; (&b.x)[e] = vb;
        }
        w1r[k * 3 + q] = a; w2r[k * 3 + q] = b;
      }
  }
  const float b3r = l3T ? B3g[0] : 0.f;
  const float w0r = (tid < 200) ? W0g[co0 * 5 + (4 - j0)] : 0.f;

  // ---- zero LDS + constant output regions ----
  for (int e = tid; e < SMF; e += NT) ((float*)&sm)[e] = 0.f;
  if (tid < 128) zml[(size_t)bi * (128 * L) + 127 * L + tid] = 0.0f;
  if (psiInterleaved) {
    float4* zp = reinterpret_cast<float4*>(psf + (size_t)bi * (2 * L * L) + 2 * L);
    const float4 nil = make_float4(0.f, 0.f, 0.f, 0.f);
    for (int j = tid; j < 16256; j += NT) zp[j] = nil;
  } else {
    float4* zp = reinterpret_cast<float4*>(psf + (size_t)bi * (L * L) + L);
    const float4 nil = make_float4(0.f, 0.f, 0.f, 0.f);
    for (int j = tid; j < 4064; j += NT) zp[j] = nil;
  }
  __syncthreads();

  // ---- constants: pre0/a0c halos; W3T ----
  if (tid < 40) {
    float s = B0g[tid];
    #pragma unroll
    for (int k = 0; k < 5; ++k) s += W0g[tid * 5 + k];
    sm.PRE0[tid] = s;
    const float a0c = fmaxf(s, 0.0f);
    #pragma unroll
    for (int r = 0; r < 4; ++r) {
      sm.A0[r * RS + tid]       = a0c;
      sm.A0[(9 + r) * RS + tid] = a0c;
    }
  }
  for (int e = tid; e < 5 * RS; e += NT) {
    const int k = e / RS, c = e - k * RS;
    sm.W3T[e] = (c < 40) ? W3g[c * 5 + k] : 0.f;
  }
  __syncthreads();
  const float pre0r = (tid < 200) ? sm.PRE0[co0] : 0.f;

  // ---- a1c (conv of constant column), halos of A1 ----
  if (convT) {
    const float4* ar = (const float4*)&sm.A0[cg * 12];
    const float4 v0 = ar[0], v1 = ar[1], v2 = ar[2];
    float4 ac0 = make_float4(0,0,0,0), ac1 = ac0, ac2 = ac0;
    #pragma unroll
    for (int k = 0; k < 5; ++k) {
      const float4 wa = w1r[k*3], wb = w1r[k*3+1], wc = w1r[k*3+2];
      ac0.x = fmaf(wa.x, v0.x, ac0.x); ac0.y = fmaf(wa.y, v0.y, ac0.y);
      ac0.z = fmaf(wa.z, v0.z, ac0.z); ac0.w = fmaf(wa.w, v0.w, ac0.w);
      ac1.x = fmaf(wb.x, v1.x, ac1.x); ac1.y = fmaf(wb.y, v1.y, ac1.y);
      ac1.z = fmaf(wb.z, v1.z, ac1.z); ac1.w = fmaf(wb.w, v1.w, ac1.w);
      ac2.x = fmaf(wc.x, v2.x, ac2.x); ac2.y = fmaf(wc.y, v2.y, ac2.y);
      ac2.z = fmaf(wc.z, v2.z, ac2.z); ac2.w = fmaf(wc.w, v2.w, ac2.w);
    }
    float red = (ac0.x+ac0.y+ac0.z+ac0.w)+(ac1.x+ac1.y+ac1.z+ac1.w)+(ac2.x+ac2.y+ac2.z+ac2.w);
    red += __shfl_xor(red, 1); red += __shfl_xor(red, 2);
    if (cg == 0 && sh == 0) {
      const float a1c = fmaxf(red + b1r, 0.0f);
      #pragma unroll
      for (int r = 0; r < 4; ++r) {
        sm.A1[r * RS + co]        = a1c;
        sm.A1[(13 + r) * RS + co] = a1c;
      }
    }
  }
  __syncthreads();

  // ---- a2c, halos of A2 ----
  if (convT) {
    const float4* ar = (const float4*)&sm.A1[cg * 12];
    const float4 v0 = ar[0], v1 = ar[1], v2 = ar[2];
    float4 ac0 = make_float4(0,0,0,0), ac1 = ac0, ac2 = ac0;
    #pragma unroll
    for (int k = 0; k < 5; ++k) {
      const float4 wa = w2r[k*3], wb = w2r[k*3+1], wc = w2r[k*3+2];
      ac0.x = fmaf(wa.x, v0.x, ac0.x); ac0.y = fmaf(wa.y, v0.y, ac0.y);
      ac0.z = fmaf(wa.z, v0.z, ac0.z); ac0.w = fmaf(wa.w, v0.w, ac0.w);
      ac1.x = fmaf(wb.x, v1.x, ac1.x); ac1.y = fmaf(wb.y, v1.y, ac1.y);
      ac1.z = fmaf(wb.z, v1.z, ac1.z); ac1.w = fmaf(wb.w, v1.w, ac1.w);
      ac2.x = fmaf(wc.x, v2.x, ac2.x); ac2.y = fmaf(wc.y, v2.y, ac2.y);
      ac2.z = fmaf(wc.z, v2.z, ac2.z); ac2.w = fmaf(wc.w, v2.w, ac2.w);
    }
    float red = (ac0.x+ac0.y+ac0.z+ac0.w)+(ac1.x+ac1.y+ac1.z+ac1.w)+(ac2.x+ac2.y+ac2.z+ac2.w);
    red += __shfl_xor(red, 1); red += __shfl_xor(red, 2);
    if (cg == 0 && sh == 0) {
      const float a2c = fmaxf(red + b2r, 0.0f);
      #pragma unroll
      for (int r = 0; r < 4; ++r) {
        sm.A2[r * RS + co]        = a2c;
        sm.A2[(17 + r) * RS + co] = a2c;
      }
    }
  }
  __syncthreads();

  // ---- vc ----
  if (l3T && s3 == 0) {
    float acc = 0.f;
    #pragma unroll
    for (int k = 0; k < 5; ++k) {
      const float4* wr = (const float4*)&sm.W3T[k * RS + cg3 * 12];
      const float4* ar = (const float4*)&sm.A2[cg3 * 12];
      #pragma unroll
      for (int q = 0; q < 3; ++q) {
        const float4 w = wr[q], a = ar[q];
        acc = fmaf(w.x, a.x, fmaf(w.y, a.y, fmaf(w.z, a.z, fmaf(w.w, a.w, acc))));
      }
    }
    acc += __shfl_xor(acc, 1); acc += __shfl_xor(acc, 2);
    if (cg3 == 0) sm.VC = acc + b3r;
  }
  __syncthreads();

  // ---- wave0 persistent state ----
  const float c0 = 0.70710678118654752440f;
  float uR0 = c0, uI0 = 0.f, uR1 = c0, uI1 = 0.f;
  float hA0 = 0.f, hA1 = 0.f, hB0 = 0.f, hB1 = 0.f, hP0 = 0.f, hP1 = 0.f;
  const int s0 = 2 * lane, s1 = s0 + 1;
  if (tid < 64) {
    const float2 h0 = *(const float2*)&hg[0 * L + s0];
    const float2 h1 = *(const float2*)&hg[1 * L + s0];
    hA0 = h0.x; hA1 = h0.y; hB0 = h1.x; hB1 = h1.y;
    if (lane == 0) sm.Z0 = 1.0f - 2.0f * (uR0 * uR0 + uI0 * uI0);
  }
  __syncthreads();

  // ================= time loop =================
  for (int t = 0; t < T; ++t) {
    if (tid < 64 && t + 2 < 128) {
      const float2 hp = *(const float2*)&hg[(t + 2) * L + s0];
      hP0 = hp.x; hP1 = hp.y;
    }
    // L0
    if (tid < 200)
      sm.A0[(j0 + 4) * RS + co0] = fmaxf(fmaf(w0r, sm.Z0 - 1.0f, pre0r), 0.0f);
    __syncthreads();

    // L1: 3 sites per thread, 7-row window preloaded
    if (convT) {
      const int baseo = -4 + sh * 3;
      float4 R[7][3];
      #pragma unroll
      for (int r = 0; r < 7; ++r) {
        const float4* ar = (const float4*)&sm.A0[(baseo + 4 + r) * RS + cg * 12];
        R[r][0] = ar[0]; R[r][1] = ar[1]; R[r][2] = ar[2];
      }
      #pragma unroll
      for (int i = 0; i < 3; ++i)
        CONV_SITE(R, i, w1r, b1r, &sm.A1[(baseo + i + 8) * RS + co]);
    }
    __syncthreads();

    // L2: 5 sites, two passes (3-site / 2-site windows)
    if (convT) {
      const int b = (sh == 0) ? -6 : ((sh == 1) ? -2 : 2);
      {
        float4 R[7][3];
        #pragma unroll
        for (int r = 0; r < 7; ++r) {
          const float4* ar = (const float4*)&sm.A1[(b + 6 + r) * RS + cg * 12];
          R[r][0] = ar[0]; R[r][1] = ar[1]; R[r][2] = ar[2];
        }
        #pragma unroll
        for (int i = 0; i < 3; ++i)
          CONV_SITE(R, i, w2r, b2r, &sm.A2[(b + i + 10) * RS + co]);
      }
      {
        float4 R[6][3];
        #pragma unroll
        for (int r = 0; r < 6; ++r) {
          const float4* ar = (const float4*)&sm.A1[(b + 9 + r) * RS + cg * 12];
          R[r][0] = ar[0]; R[r][1] = ar[1]; R[r][2] = ar[2];
        }
        // FIX (was CONV_SITE(R, i+1)): site b+3 uses window rows 0..4,
        // site b+4 uses rows 1..5.
        #pragma unroll
        for (int i = 0; i < 2; ++i)
          CONV_SITE(R, i, w2r, b2r, &sm.A2[(b + i + 13) * RS + co]);
      }
    }
    __syncthreads();

    // L3: 17 sites x 4 cg, act window preloaded, weights broadcast from LDS
    if (l3T) {
      float4 AR[5][3];
      #pragma unroll
      for (int k = 0; k < 5; ++k) {
        const float4* ar = (const float4*)&sm.A2[(s3 + k) * RS + cg3 * 12];
        AR[k][0] = ar[0]; AR[k][1] = ar[1]; AR[k][2] = ar[2];
      }
      float4 ac = make_float4(0,0,0,0);
      float4 ac2 = ac, ac3 = ac;
      #pragma unroll
      for (int k = 0; k < 5; ++k) {
        const float4* wr = (const float4*)&sm.W3T[k * RS + cg3 * 12];
        const float4 w0 = wr[0], w1 = wr[1], w2 = wr[2];
        ac.x  = fmaf(w0.x, AR[k][0].x, ac.x);  ac.y  = fmaf(w0.y, AR[k][0].y, ac.y);
        ac.z  = fmaf(w0.z, AR[k][0].z, ac.z);  ac.w  = fmaf(w0.w, AR[k][0].w, ac.w);
        ac2.x = fmaf(w1.x, AR[k][1].x, ac2.x); ac2.y = fmaf(w1.y, AR[k][1].y, ac2.y);
        ac2.z = fmaf(w1.z, AR[k][1].z, ac2.z); ac2.w = fmaf(w1.w, AR[k][1].w, ac2.w);
        ac3.x = fmaf(w2.x, AR[k][2].x, ac3.x); ac3.y = fmaf(w2.y, AR[k][2].y, ac3.y);
        ac3.z = fmaf(w2.z, AR[k][2].z, ac3.z); ac3.w = fmaf(w2.w, AR[k][2].w, ac3.w);
      }
      float acc = (ac.x+ac.y+ac.z+ac.w) + (ac2.x+ac2.y+ac2.z+ac2.w)
                + (ac3.x+ac3.y+ac3.z+ac3.w);
      acc += __shfl_xor(acc, 1); acc += __shfl_xor(acc, 2);
      if (cg3 == 0) sm.V[s3] = acc + b3r;
    }
    __syncthreads();

    // RK4 + mag + z0 (wave0 registers)
    if (tid < 64) {
      float v0 = sm.VC, v1 = sm.VC;
      if (s0 <= 8) v0 = sm.V[s0 + 8]; else if (s0 >= 120) v0 = sm.V[s0 - 120];
      if (s1 <= 8) v1 = sm.V[s1 + 8]; else if (s1 >= 120) v1 = sm.V[s1 - 120];
      const float f10 = v0 + hA0, f11 = v1 + hA1;
      const float f40 = v0 + hB0, f41 = v1 + hB1;

      float y0R = uR0, y0I = uI0, y1R = uR1, y1I = uI1;
      float aR0 = 0.f, aI0 = 0.f, aR1 = 0.f, aI1 = 0.f;
      #pragma unroll
      for (int st = 0; st < 4; ++st) {
        const bool fin = (st == 3);
        const float f0 = fin ? f40 : f10;
        const float f1 = fin ? f41 : f11;
        const float ymR = __shfl(y1R, (lane + 63) & 63);
        const float ymI = __shfl(y1I, (lane + 63) & 63);
        const float ypR = __shfl(y0R, (lane + 1) & 63);
        const float ypI = __shfl(y0I, (lane + 1) & 63);
        const float d0 = 2.0f + f0, d1 = 2.0f + f1;
        const float hRa = fmaf(d0, y0R, -ymR) - y1R;
        const float hIa = fmaf(d0, y0I, -ymI) - y1I;
        const float hRb = fmaf(d1, y1R, -y0R) - ypR;
        const float hIb = fmaf(d1, y1I, -y0I) - ypI;
        const float kR0 = hIa, kI0 = -hRa, kR1 = hIb, kI1 = -hRb;
        if (st == 0) { aR0 = dt * kR0; aI0 = dt * kI0; aR1 = dt * kR1; aI1 = dt * kI1; }
        else {
          const float w = fin ? 1.0f : 2.0f;
          aR0 = fmaf(w, kR0, aR0); aI0 = fmaf(w, kI0, aI0);
          aR1 = fmaf(w, kR1, aR1); aI1 = fmaf(w, kI1, aI1);
        }
        if (fin) {
          uR0 = fmaf(dtS, aR0, uR0); uI0 = fmaf(dtS, aI0, uI0);
          uR1 = fmaf(dtS, aR1, uR1); uI1 = fmaf(dtS, aI1, uI1);
        } else {
          const float stp = (st == 2) ? dt : dtH;
          y0R = fmaf(stp, kR0, uR0); y0I = fmaf(stp, kI0, uI0);
          y1R = fmaf(stp, kR1, uR1); y1I = fmaf(stp, kI1, uI1);
        }
      }
      const float m0 = 1.0f - 2.0f * (uR0 * uR0 + uI0 * uI0);
      const float m1 = 1.0f - 2.0f * (uR1 * uR1 + uI1 * uI1);
      *(float2*)&zml[(size_t)bi * (128 * L) + (size_t)(126 - t) * L + s0] =
          make_float2(m0, m1);
      if (lane == 0) sm.Z0 = m0;
      hA0 = hB0; hA1 = hB1; hB0 = hP0; hB1 = hP1;
    }
    __syncthreads();
  }

  // ---- final psi row 0 ----
  if (tid < 64) {
    if (psiInterleaved) {
      *(float4*)&psf[(size_t)bi * (2 * L * L) + 4 * lane] =
          make_float4(uR0, uI0, uR1, uI1);
    } else {
      *(float2*)&psf[(size_t)bi * (L * L) + s0] = make_float2(uR0, uR1);
    }
  }
}

extern "C" void kernel_launch(void* const* d_in, const int* in_sizes, int n_in,
                              void* d_out, int out_size, void* d_ws, size_t ws_size,
                              hipStream_t stream) {
  (void)d_ws; (void)ws_size;
  using namespace v14;

  const float* in[9] = {nullptr};
  int seen200 = 0, seen40 = 0, seen8000 = 0;
  for (int i = 0; i < n_in && i < 16; ++i) {
    const int sz = in_sizes[i];
    const float* q = (const float*)d_in[i];
    if      (sz == 2097152) in[0] = q;
    else if (sz == 8000)    { in[seen8000 ? 5 : 3] = q; ++seen8000; }
    else if (sz == 200)     { in[seen200  ? 7 : 1] = q; ++seen200;  }
    else if (sz == 40)      { in[seen40 == 0 ? 2 : (seen40 == 1 ? 4 : 6)] = q; ++seen40; }
    else if (sz == 1)       in[8] = q;
  }
  bool ok = true;
  for (int i = 0; i < 9; ++i) ok = ok && (in[i] != nullptr);
  if (!ok) for (int i = 0; i < 9; ++i) in[i] = (const float*)d_in[i];

  const size_t zCount = (size_t)B * 128 * L;
  const long long psiFloats = (long long)out_size - (long long)zCount;
  const int psiInterleaved = (psiFloats >= (long long)2 * L * L * B) ? 1 : 0;

  float* zml = (float*)d_out;
  float* psf = zml + zCount;
  const float dt = (float)(6.4 / 127.0);

  hipLaunchKernelGGL(adia_v14, dim3(B), dim3(NT), 0, stream,
                     in[0], in[1], in[2], in[3], in[4], in[5], in[6], in[7], in[8],
                     zml, psf, psiInterleaved, dt);
}